// Round 13
// baseline (152.759 us; speedup 1.0000x reference)
//
#include <hip/hip_runtime.h>
#include <cmath>

#define NB 4
#define NS 1024
#define NH 16
#define ND 64
#define LOG2E 1.44269504f

typedef __attribute__((ext_vector_type(8))) short bf16x8;
typedef __attribute__((ext_vector_type(4))) float f32x4;

static __device__ __forceinline__ short f2bf(float x) {
  __bf16 h = (__bf16)x;
  return __builtin_bit_cast(short, h);
}

static __device__ __forceinline__ float fast_exp2(float x) {
#if __has_builtin(__builtin_amdgcn_exp2f)
  return __builtin_amdgcn_exp2f(x);
#else
  return exp2f(x);
#endif
}

__global__ __launch_bounds__(512, 4)
void fsa_fwd(const float* __restrict__ qkv,
             const float* __restrict__ bias,
             float* __restrict__ out)
{
  // XCD-chunked swizzle, batch-fastest logical order. grid=512, bijective.
  const int hw = blockIdx.x;
  const int lg = ((hw & 7) << 6) | (hw >> 3);
  const int b  = lg & 3;
  const int qt = (lg >> 2) & 7;       // 8 q-tiles of 128 rows
  const int h  = lg >> 5;

  const int tid  = threadIdx.x;
  const int w    = tid >> 6;          // wave 0..7
  const int half = w >> 2;            // KV half: waves 0-3 -> t[0,512), waves 4-7 -> t[512,1024)
  const int wq   = w & 3;             // 32-row q-subtile within the 128-row q-tile
  const int lane = tid & 63;
  const int lo   = lane & 15;
  const int hi   = lane >> 4;
  const int q0   = qt * 128;

  __shared__ __attribute__((aligned(16))) short Ksh[2][64 * 64];   // per-half K tile (16 KB)
  __shared__ __attribute__((aligned(16))) short VTsh[2][64 * 64];  // per-half V^T tile (16 KB)
  __shared__ __attribute__((aligned(16))) short Psh[8][32 * 64];   // per-wave P strip (32 KB); f32 combine buf in epilogue

  // ---- Q fragments for 2 strips (A-operand), pre-scaled by 0.125*log2e ----
  bf16x8 qf[2][2];
  #pragma unroll
  for (int s = 0; s < 2; ++s) {
    const int qs = q0 + wq * 32 + s * 16 + lo;
    const float* qp = qkv + ((size_t)(b * NS + qs) * 3) * (NH * ND) + h * ND + hi * 8;
    #pragma unroll
    for (int f = 0; f < 2; ++f) {
      float4 x0 = *(const float4*)(qp + f * 32);
      float4 x1 = *(const float4*)(qp + f * 32 + 4);
      float v[8] = {x0.x, x0.y, x0.z, x0.w, x1.x, x1.y, x1.z, x1.w};
      #pragma unroll
      for (int j = 0; j < 8; ++j) qf[s][f][j] = f2bf(v[j] * (0.125f * LOG2E));
    }
  }

  const size_t tstr = 3 * NH * ND;  // 3072 floats per s-step
  const float* kg = qkv + (size_t)b * NS * tstr + 1 * NH * ND + h * ND;
  const float* vg = qkv + (size_t)b * NS * tstr + 2 * NH * ND + h * ND;

  // staging: group g = tid>>8 stages the tile for KV-half g (R3-proven patterns, 256 thr/tile)
  const int g    = tid >> 8;
  const int stid = tid & 255;
  const int krow = stid >> 2;          // 0..63
  const int kd   = (stid & 3) * 16;    // 16 floats
  const int vrow = (stid & 31) * 2;    // t pair
  const int vd   = (stid >> 5) * 8;    // 8 d's

  const float* bb = bias + (size_t)h * NS * NS + (size_t)(q0 + wq * 32) * NS + half * 512;

  float psum[2][4];
  f32x4 oacc[2][4];
  #pragma unroll
  for (int s = 0; s < 2; ++s)
    #pragma unroll
    for (int dt = 0; dt < 4; ++dt) {
      f32x4 z = {0.f, 0.f, 0.f, 0.f};
      oacc[s][dt] = z;
      psum[s][dt] = 0.f;
    }

  #pragma unroll 1
  for (int it = 0; it < 8; ++it) {
    __syncthreads();  // prior iteration's K/VT LDS reads complete

    // ---- stage K tile for half g (use-site loads, R3 pattern) ----
    {
      const float* src = kg + (size_t)(g * 512 + it * 64 + krow) * tstr + kd;
      float4 a = ((const float4*)src)[0];
      float4 c = ((const float4*)src)[1];
      float4 e = ((const float4*)src)[2];
      float4 q4 = ((const float4*)src)[3];
      float v[16] = {a.x,a.y,a.z,a.w, c.x,c.y,c.z,c.w, e.x,e.y,e.z,e.w, q4.x,q4.y,q4.z,q4.w};
      bf16x8 w0, w1;
      #pragma unroll
      for (int j = 0; j < 8; ++j) { w0[j] = f2bf(v[j]); w1[j] = f2bf(v[8 + j]); }
      const int base = krow * 64 + kd;
      const int sw = (krow & 7) << 3;
      *(bf16x8*)&Ksh[g][(base    ) ^ sw] = w0;
      *(bf16x8*)&Ksh[g][(base + 8) ^ sw] = w1;
    }
    // ---- stage V tile transposed for half g ----
    {
      const float* s0 = vg + (size_t)(g * 512 + it * 64 + vrow) * tstr + vd;
      const float* s1 = s0 + tstr;
      float4 a0 = ((const float4*)s0)[0], a1 = ((const float4*)s0)[1];
      float4 b0 = ((const float4*)s1)[0], b1 = ((const float4*)s1)[1];
      float r0[8] = {a0.x,a0.y,a0.z,a0.w, a1.x,a1.y,a1.z,a1.w};
      float r1[8] = {b0.x,b0.y,b0.z,b0.w, b1.x,b1.y,b1.z,b1.w};
      unsigned* vt32 = (unsigned*)VTsh[g];
      #pragma unroll
      for (int j = 0; j < 8; ++j) {
        unsigned pk = (unsigned)(unsigned short)f2bf(r0[j]) |
                      ((unsigned)(unsigned short)f2bf(r1[j]) << 16);
        const int R = vd + j;
        vt32[R * 32 + ((vrow >> 1) ^ ((R & 7) << 2))] = pk;
      }
    }

    // ---- bias loads straight into sacc (in flight across the barrier) ----
    f32x4 sacc[2][4];
    #pragma unroll
    for (int s = 0; s < 2; ++s)
      #pragma unroll
      for (int tt = 0; tt < 4; ++tt)
        #pragma unroll
        for (int r = 0; r < 4; ++r)
          sacc[s][tt][r] = bb[(size_t)(s * 16 + hi * 4 + r) * NS + it * 64 + tt * 16 + lo];

    __syncthreads();  // K/VT tiles visible

    // scale bias: s = b*log2e - 8*log2e (one FMA each)
    #pragma unroll
    for (int s = 0; s < 2; ++s)
      #pragma unroll
      for (int tt = 0; tt < 4; ++tt)
        #pragma unroll
        for (int r = 0; r < 4; ++r)
          sacc[s][tt][r] = fmaf(sacc[s][tt][r], LOG2E, -8.f * LOG2E);

    __builtin_amdgcn_s_setprio(1);
    // ---- QK^T: K frags read once, reused by both strips ----
    #pragma unroll
    for (int tt = 0; tt < 4; ++tt) {
      const int kr = tt * 16 + lo;
      const int ksw = (kr & 7) << 3;
      bf16x8 k0 = *(const bf16x8*)&Ksh[half][(kr * 64      + hi * 8) ^ ksw];
      bf16x8 k1 = *(const bf16x8*)&Ksh[half][(kr * 64 + 32 + hi * 8) ^ ksw];
      sacc[0][tt] = __builtin_amdgcn_mfma_f32_16x16x32_bf16(qf[0][0], k0, sacc[0][tt], 0, 0, 0);
      sacc[1][tt] = __builtin_amdgcn_mfma_f32_16x16x32_bf16(qf[1][0], k0, sacc[1][tt], 0, 0, 0);
      sacc[0][tt] = __builtin_amdgcn_mfma_f32_16x16x32_bf16(qf[0][1], k1, sacc[0][tt], 0, 0, 0);
      sacc[1][tt] = __builtin_amdgcn_mfma_f32_16x16x32_bf16(qf[1][1], k1, sacc[1][tt], 0, 0, 0);
    }

    // ---- P = exp2(s), per-lane f32 psum, per-wave P strip (32 rows) ----
    short* pw = Psh[w];
    #pragma unroll
    for (int s = 0; s < 2; ++s)
      #pragma unroll
      for (int r = 0; r < 4; ++r) {
        const int row = s * 16 + hi * 4 + r;
        const int sw = (row & 7) << 3;
        #pragma unroll
        for (int tt = 0; tt < 4; ++tt) {
          float p = fast_exp2(sacc[s][tt][r]);
          psum[s][r] += p;
          pw[row * 64 + ((tt * 16 + lo) ^ sw)] = f2bf(p);
        }
      }
    asm volatile("s_waitcnt lgkmcnt(0)" ::: "memory");

    // ---- PV: VT frags read once, reused by both strips ----
    bf16x8 pf[2][2];
    {
      const int psw = (lo & 7) << 3;
      #pragma unroll
      for (int s = 0; s < 2; ++s) {
        pf[s][0] = *(const bf16x8*)&pw[(s * 16 + lo) * 64 + ((     hi * 8) ^ psw)];
        pf[s][1] = *(const bf16x8*)&pw[(s * 16 + lo) * 64 + ((32 + hi * 8) ^ psw)];
      }
    }
    #pragma unroll
    for (int dt = 0; dt < 4; ++dt) {
      const int vr = dt * 16 + lo;
      const int vsw = (vr & 7) << 3;
      bf16x8 v0 = *(const bf16x8*)&VTsh[half][vr * 64 + ((     hi * 8) ^ vsw)];
      bf16x8 v1 = *(const bf16x8*)&VTsh[half][vr * 64 + ((32 + hi * 8) ^ vsw)];
      oacc[0][dt] = __builtin_amdgcn_mfma_f32_16x16x32_bf16(pf[0][0], v0, oacc[0][dt], 0, 0, 0);
      oacc[1][dt] = __builtin_amdgcn_mfma_f32_16x16x32_bf16(pf[1][0], v0, oacc[1][dt], 0, 0, 0);
      oacc[0][dt] = __builtin_amdgcn_mfma_f32_16x16x32_bf16(pf[0][1], v1, oacc[0][dt], 0, 0, 0);
      oacc[1][dt] = __builtin_amdgcn_mfma_f32_16x16x32_bf16(pf[1][1], v1, oacc[1][dt], 0, 0, 0);
    }
    __builtin_amdgcn_s_setprio(0);
  }

  // ---- psum reduce over the 16 lo lanes ----
  #pragma unroll
  for (int s = 0; s < 2; ++s)
    #pragma unroll
    for (int r = 0; r < 4; ++r) {
      psum[s][r] += __shfl_xor(psum[s][r], 1, 64);
      psum[s][r] += __shfl_xor(psum[s][r], 2, 64);
      psum[s][r] += __shfl_xor(psum[s][r], 4, 64);
      psum[s][r] += __shfl_xor(psum[s][r], 8, 64);
    }

  // ---- combine the two KV halves (const-shift => pure add) ----
  __syncthreads();  // all P-strip traffic done; reuse LDS
  float* osh = (float*)&Psh[0][0];          // 4 pairs x 32 rows x 64 cols f32 = 32 KB
  float* psh = (float*)&Ksh[0][0];          // 4 pairs x 32 rows f32
  if (half == 1) {
    #pragma unroll
    for (int s = 0; s < 2; ++s)
      #pragma unroll
      for (int r = 0; r < 4; ++r) {
        const int row = s * 16 + hi * 4 + r;
        #pragma unroll
        for (int dt = 0; dt < 4; ++dt)
          osh[wq * 2048 + row * 64 + dt * 16 + lo] = oacc[s][dt][r];
        if (lo == 0) psh[wq * 32 + row] = psum[s][r];
      }
  }
  __syncthreads();
  if (half == 0) {
    #pragma unroll
    for (int s = 0; s < 2; ++s)
      #pragma unroll
      for (int r = 0; r < 4; ++r) {
        const int row = s * 16 + hi * 4 + r;
        const float inv = 1.f / (psum[s][r] + psh[wq * 32 + row]);
        float* ob = out + ((size_t)(b * NS + q0 + wq * 32 + row) * NH + h) * ND + lo;
        #pragma unroll
        for (int dt = 0; dt < 4; ++dt)
          ob[dt * 16] = (oacc[s][dt][r] + osh[wq * 2048 + row * 64 + dt * 16 + lo]) * inv;
      }
  }
}

extern "C" void kernel_launch(void* const* d_in, const int* in_sizes, int n_in,
                              void* d_out, int out_size, void* d_ws, size_t ws_size,
                              hipStream_t stream) {
  const float* qkv  = (const float*)d_in[0];
  const float* bias = (const float*)d_in[1];
  float* out = (float*)d_out;
  dim3 grid(NB * NH * (NS / 128));
  fsa_fwd<<<grid, 512, 0, stream>>>(qkv, bias, out);
}

// Round 14
// 80.199 us; speedup vs baseline: 1.9048x; 1.9048x over previous
//
#include <hip/hip_runtime.h>
#include <cmath>

#define NB 4
#define NS 1024
#define NH 16
#define ND 64
#define LOG2E 1.44269504f

typedef __attribute__((ext_vector_type(8))) short bf16x8;
typedef __attribute__((ext_vector_type(4))) float f32x4;

static __device__ __forceinline__ short f2bf(float x) {
  __bf16 h = (__bf16)x;
  return __builtin_bit_cast(short, h);
}

static __device__ __forceinline__ float fast_exp2(float x) {
#if __has_builtin(__builtin_amdgcn_exp2f)
  return __builtin_amdgcn_exp2f(x);
#else
  return exp2f(x);
#endif
}

__global__ __launch_bounds__(512, 2)
void fsa_fwd(const float* __restrict__ qkv,
             const float* __restrict__ bias,
             float* __restrict__ out)
{
  // XCD-chunked swizzle, batch-fastest logical order. grid=512, bijective.
  const int hw = blockIdx.x;
  const int lg = ((hw & 7) << 6) | (hw >> 3);
  const int b  = lg & 3;
  const int qt = (lg >> 2) & 7;       // 8 q-tiles of 128 rows
  const int h  = lg >> 5;

  const int tid  = threadIdx.x;
  const int w    = tid >> 6;          // wave 0..7
  const int half = w >> 2;            // KV half: waves 0-3 -> t[0,512), 4-7 -> t[512,1024)
  const int wq   = w & 3;             // 32-row q-subtile
  const int lane = tid & 63;
  const int lo   = lane & 15;
  const int hi   = lane >> 4;
  const int q0   = qt * 128;

  __shared__ __attribute__((aligned(16))) short Ksh[2][64 * 64];   // per-half K tile (16 KB)
  __shared__ __attribute__((aligned(16))) short VTsh[2][64 * 64];  // per-half V^T tile (16 KB)
  __shared__ __attribute__((aligned(16))) short Psh[8][32 * 64];   // per-wave P strip (32 KB)

  // ---- Q fragments for 2 strips (A-operand), pre-scaled by 0.125*log2e ----
  bf16x8 qf[2][2];
  #pragma unroll
  for (int s = 0; s < 2; ++s) {
    const int qs = q0 + wq * 32 + s * 16 + lo;
    const float* qp = qkv + ((size_t)(b * NS + qs) * 3) * (NH * ND) + h * ND + hi * 8;
    #pragma unroll
    for (int f = 0; f < 2; ++f) {
      float4 x0 = *(const float4*)(qp + f * 32);
      float4 x1 = *(const float4*)(qp + f * 32 + 4);
      float v[8] = {x0.x, x0.y, x0.z, x0.w, x1.x, x1.y, x1.z, x1.w};
      #pragma unroll
      for (int j = 0; j < 8; ++j) qf[s][f][j] = f2bf(v[j] * (0.125f * LOG2E));
    }
  }

  const size_t tstr = 3 * NH * ND;  // 3072 floats per s-step
  const float* kg = qkv + (size_t)b * NS * tstr + 1 * NH * ND + h * ND;
  const float* vg = qkv + (size_t)b * NS * tstr + 2 * NH * ND + h * ND;

  // staging: group g = tid>>8 stages the tile for KV-half g (256 thr/tile, R3 pattern)
  const int g    = tid >> 8;
  const int stid = tid & 255;
  const int krow = stid >> 2;          // 0..63
  const int kd   = (stid & 3) * 16;    // 16 floats
  const int vrow = (stid & 31) * 2;    // t pair
  const int vd   = (stid >> 5) * 8;    // 8 d's

  const float* bb = bias + (size_t)h * NS * NS + (size_t)(q0 + wq * 32) * NS + half * 512;

  float psum[2][4];
  f32x4 oacc[2][4];
  #pragma unroll
  for (int s = 0; s < 2; ++s)
    #pragma unroll
    for (int dt = 0; dt < 4; ++dt) {
      f32x4 z = {0.f, 0.f, 0.f, 0.f};
      oacc[s][dt] = z;
      psum[s][dt] = 0.f;
    }

  #pragma unroll 1
  for (int it = 0; it < 8; ++it) {
    __syncthreads();  // prior iteration's K/VT LDS reads complete

    // ---- stage K tile for half g (use-site loads, R3 pattern) ----
    {
      const float* src = kg + (size_t)(g * 512 + it * 64 + krow) * tstr + kd;
      float4 a = ((const float4*)src)[0];
      float4 c = ((const float4*)src)[1];
      float4 e = ((const float4*)src)[2];
      float4 q4 = ((const float4*)src)[3];
      float v[16] = {a.x,a.y,a.z,a.w, c.x,c.y,c.z,c.w, e.x,e.y,e.z,e.w, q4.x,q4.y,q4.z,q4.w};
      bf16x8 w0, w1;
      #pragma unroll
      for (int j = 0; j < 8; ++j) { w0[j] = f2bf(v[j]); w1[j] = f2bf(v[8 + j]); }
      const int base = krow * 64 + kd;
      const int sw = (krow & 7) << 3;
      *(bf16x8*)&Ksh[g][(base    ) ^ sw] = w0;
      *(bf16x8*)&Ksh[g][(base + 8) ^ sw] = w1;
    }
    // ---- stage V tile transposed for half g ----
    {
      const float* s0 = vg + (size_t)(g * 512 + it * 64 + vrow) * tstr + vd;
      const float* s1 = s0 + tstr;
      float4 a0 = ((const float4*)s0)[0], a1 = ((const float4*)s0)[1];
      float4 b0 = ((const float4*)s1)[0], b1 = ((const float4*)s1)[1];
      float r0[8] = {a0.x,a0.y,a0.z,a0.w, a1.x,a1.y,a1.z,a1.w};
      float r1[8] = {b0.x,b0.y,b0.z,b0.w, b1.x,b1.y,b1.z,b1.w};
      unsigned* vt32 = (unsigned*)VTsh[g];
      #pragma unroll
      for (int j = 0; j < 8; ++j) {
        unsigned pk = (unsigned)(unsigned short)f2bf(r0[j]) |
                      ((unsigned)(unsigned short)f2bf(r1[j]) << 16);
        const int R = vd + j;
        vt32[R * 32 + ((vrow >> 1) ^ ((R & 7) << 2))] = pk;
      }
    }

    __syncthreads();  // K/VT tiles visible

    // ---- bias at use-site into sacc: s = bias*log2e - 8*log2e ----
    f32x4 sacc[2][4];
    #pragma unroll
    for (int s = 0; s < 2; ++s)
      #pragma unroll
      for (int tt = 0; tt < 4; ++tt)
        #pragma unroll
        for (int r = 0; r < 4; ++r)
          sacc[s][tt][r] = fmaf(bb[(size_t)(s * 16 + hi * 4 + r) * NS + it * 64 + tt * 16 + lo],
                                LOG2E, -8.f * LOG2E);

    __builtin_amdgcn_s_setprio(1);
    // ---- QK^T: K frags read once, reused by both strips ----
    #pragma unroll
    for (int tt = 0; tt < 4; ++tt) {
      const int kr = tt * 16 + lo;
      const int ksw = (kr & 7) << 3;
      bf16x8 k0 = *(const bf16x8*)&Ksh[half][(kr * 64      + hi * 8) ^ ksw];
      bf16x8 k1 = *(const bf16x8*)&Ksh[half][(kr * 64 + 32 + hi * 8) ^ ksw];
      sacc[0][tt] = __builtin_amdgcn_mfma_f32_16x16x32_bf16(qf[0][0], k0, sacc[0][tt], 0, 0, 0);
      sacc[1][tt] = __builtin_amdgcn_mfma_f32_16x16x32_bf16(qf[1][0], k0, sacc[1][tt], 0, 0, 0);
      sacc[0][tt] = __builtin_amdgcn_mfma_f32_16x16x32_bf16(qf[0][1], k1, sacc[0][tt], 0, 0, 0);
      sacc[1][tt] = __builtin_amdgcn_mfma_f32_16x16x32_bf16(qf[1][1], k1, sacc[1][tt], 0, 0, 0);
    }

    // ---- P = exp2(s), per-lane f32 psum, per-wave 32-row P strip ----
    short* pw = Psh[w];
    #pragma unroll
    for (int s = 0; s < 2; ++s)
      #pragma unroll
      for (int r = 0; r < 4; ++r) {
        const int row = s * 16 + hi * 4 + r;
        const int sw = (row & 7) << 3;
        #pragma unroll
        for (int tt = 0; tt < 4; ++tt) {
          float p = fast_exp2(sacc[s][tt][r]);
          psum[s][r] += p;
          pw[row * 64 + ((tt * 16 + lo) ^ sw)] = f2bf(p);
        }
      }
    asm volatile("s_waitcnt lgkmcnt(0)" ::: "memory");

    // ---- PV: VT frags read once, reused by both strips ----
    bf16x8 pf[2][2];
    {
      const int psw = (lo & 7) << 3;
      #pragma unroll
      for (int s = 0; s < 2; ++s) {
        pf[s][0] = *(const bf16x8*)&pw[(s * 16 + lo) * 64 + ((     hi * 8) ^ psw)];
        pf[s][1] = *(const bf16x8*)&pw[(s * 16 + lo) * 64 + ((32 + hi * 8) ^ psw)];
      }
    }
    #pragma unroll
    for (int dt = 0; dt < 4; ++dt) {
      const int vr = dt * 16 + lo;
      const int vsw = (vr & 7) << 3;
      bf16x8 v0 = *(const bf16x8*)&VTsh[half][vr * 64 + ((     hi * 8) ^ vsw)];
      bf16x8 v1 = *(const bf16x8*)&VTsh[half][vr * 64 + ((32 + hi * 8) ^ vsw)];
      oacc[0][dt] = __builtin_amdgcn_mfma_f32_16x16x32_bf16(pf[0][0], v0, oacc[0][dt], 0, 0, 0);
      oacc[1][dt] = __builtin_amdgcn_mfma_f32_16x16x32_bf16(pf[1][0], v0, oacc[1][dt], 0, 0, 0);
      oacc[0][dt] = __builtin_amdgcn_mfma_f32_16x16x32_bf16(pf[0][1], v1, oacc[0][dt], 0, 0, 0);
      oacc[1][dt] = __builtin_amdgcn_mfma_f32_16x16x32_bf16(pf[1][1], v1, oacc[1][dt], 0, 0, 0);
    }
    __builtin_amdgcn_s_setprio(0);
  }

  // ---- psum reduce over the 16 lo lanes ----
  #pragma unroll
  for (int s = 0; s < 2; ++s)
    #pragma unroll
    for (int r = 0; r < 4; ++r) {
      psum[s][r] += __shfl_xor(psum[s][r], 1, 64);
      psum[s][r] += __shfl_xor(psum[s][r], 2, 64);
      psum[s][r] += __shfl_xor(psum[s][r], 4, 64);
      psum[s][r] += __shfl_xor(psum[s][r], 8, 64);
    }

  // ---- combine the two KV halves (const-shift => pure add) ----
  __syncthreads();  // all P-strip traffic done; reuse LDS
  float* osh = (float*)&Psh[0][0];          // 4 wq x 32 rows x 64 cols f32 = 32 KB
  float* psh = (float*)&Ksh[0][0];          // 4 wq x 32 rows f32
  if (half == 1) {
    #pragma unroll
    for (int s = 0; s < 2; ++s)
      #pragma unroll
      for (int r = 0; r < 4; ++r) {
        const int row = s * 16 + hi * 4 + r;
        #pragma unroll
        for (int dt = 0; dt < 4; ++dt)
          osh[wq * 2048 + row * 64 + dt * 16 + lo] = oacc[s][dt][r];
        if (lo == 0) psh[wq * 32 + row] = psum[s][r];
      }
  }
  __syncthreads();
  if (half == 0) {
    #pragma unroll
    for (int s = 0; s < 2; ++s)
      #pragma unroll
      for (int r = 0; r < 4; ++r) {
        const int row = s * 16 + hi * 4 + r;
        const float inv = 1.f / (psum[s][r] + psh[wq * 32 + row]);
        float* ob = out + ((size_t)(b * NS + q0 + wq * 32 + row) * NH + h) * ND + lo;
        #pragma unroll
        for (int dt = 0; dt < 4; ++dt)
          ob[dt * 16] = (oacc[s][dt][r] + osh[wq * 2048 + row * 64 + dt * 16 + lo]) * inv;
      }
  }
}

extern "C" void kernel_launch(void* const* d_in, const int* in_sizes, int n_in,
                              void* d_out, int out_size, void* d_ws, size_t ws_size,
                              hipStream_t stream) {
  const float* qkv  = (const float*)d_in[0];
  const float* bias = (const float*)d_in[1];
  float* out = (float*)d_out;
  dim3 grid(NB * NH * (NS / 128));
  fsa_fwd<<<grid, 512, 0, stream>>>(qkv, bias, out);
}

// Round 15
// 50.510 us; speedup vs baseline: 3.0244x; 1.5878x over previous
//
#include <hip/hip_runtime.h>
#include <cmath>

#define NB 4
#define NS 1024
#define NH 16
#define ND 64
#define LOG2E 1.44269504f

typedef __attribute__((ext_vector_type(8))) short bf16x8;
typedef __attribute__((ext_vector_type(4))) short bf16x4;
typedef __attribute__((ext_vector_type(4))) float f32x4;

static __device__ __forceinline__ short f2bf(float x) {
  __bf16 h = (__bf16)x;
  return __builtin_bit_cast(short, h);
}

static __device__ __forceinline__ float fast_exp2(float x) {
#if __has_builtin(__builtin_amdgcn_exp2f)
  return __builtin_amdgcn_exp2f(x);
#else
  return exp2f(x);
#endif
}

__global__ __launch_bounds__(1024, 4)
void fsa_fwd(const float* __restrict__ qkv,
             const float* __restrict__ bias,
             float* __restrict__ out)
{
  // XCD-chunked swizzle, batch-fastest logical order. grid=256, cpx=32, bijective.
  const int hw = blockIdx.x;
  const int lg = ((hw & 7) << 5) | (hw >> 3);
  const int b  = lg & 3;
  const int qt = (lg >> 2) & 3;       // 4 q-tiles of 256 rows
  const int h  = lg >> 4;

  const int tid  = threadIdx.x;
  const int w    = tid >> 6;          // wave 0..15, owns q-rows q0+w*16..+15
  const int lane = tid & 63;
  const int lo   = lane & 15;
  const int hi   = lane >> 4;
  const int q0   = qt * 256;

  __shared__ __attribute__((aligned(16))) short Ksh[64 * 64];    // [t][d] XOR-swizzled rows (8 KB)
  __shared__ __attribute__((aligned(16))) short VTsh[64 * 64];   // [d][t] packed-pair XOR-swizzled (8 KB)
  __shared__ __attribute__((aligned(16))) short Psh[16][16 * 64];// per-wave P strip (32 KB)

  // ---- Q fragments (A-operand), pre-scaled by 0.125*log2e ----
  bf16x8 qf[2];
  {
    const int qs = q0 + w * 16 + lo;
    const float* qp = qkv + ((size_t)(b * NS + qs) * 3) * (NH * ND) + h * ND + hi * 8;
    #pragma unroll
    for (int f = 0; f < 2; ++f) {
      float4 x0 = *(const float4*)(qp + f * 32);
      float4 x1 = *(const float4*)(qp + f * 32 + 4);
      float v[8] = {x0.x, x0.y, x0.z, x0.w, x1.x, x1.y, x1.z, x1.w};
      #pragma unroll
      for (int j = 0; j < 8; ++j) qf[f][j] = f2bf(v[j] * (0.125f * LOG2E));
    }
  }

  const size_t tstr = 3 * NH * ND;  // 3072 floats per s-step
  const float* kg = qkv + (size_t)b * NS * tstr + 1 * NH * ND + h * ND;
  const float* vg = qkv + (size_t)b * NS * tstr + 2 * NH * ND + h * ND;

  // staging split across 1024 threads (4 floats each)
  const int krow = tid >> 4;          // 0..63
  const int kd   = (tid & 15) * 4;    // 4 floats per thread
  const int vrow = (tid & 31) * 2;    // t pair
  const int vd   = (tid >> 5) * 2;    // 2 d's per thread

  const float* bb = bias + (size_t)h * NS * NS + (size_t)(q0 + w * 16 + hi * 4) * NS + lo;

  float psum[4] = {0.f, 0.f, 0.f, 0.f};
  f32x4 oacc[4];
  #pragma unroll
  for (int dt = 0; dt < 4; ++dt) { f32x4 z = {0.f, 0.f, 0.f, 0.f}; oacc[dt] = z; }

  #pragma unroll 1
  for (int it = 0; it < 16; ++it) {
    const int t0 = it * 64;

    // ---- load + convert K rows (4 f32 -> 1 b64 write) ----
    bf16x4 kw;
    {
      const float* src = kg + (size_t)(t0 + krow) * tstr + kd;
      float4 a = *(const float4*)src;
      float v[4] = {a.x, a.y, a.z, a.w};
      #pragma unroll
      for (int j = 0; j < 4; ++j) kw[j] = f2bf(v[j]);
    }
    // ---- load + convert V (2 t-rows x 2 d, packed pairs) ----
    unsigned vpk[2];
    {
      const float* s0 = vg + (size_t)(t0 + vrow) * tstr + vd;
      const float* s1 = s0 + tstr;
      float2 a0 = *(const float2*)s0;
      float2 b0 = *(const float2*)s1;
      vpk[0] = (unsigned)(unsigned short)f2bf(a0.x) | ((unsigned)(unsigned short)f2bf(b0.x) << 16);
      vpk[1] = (unsigned)(unsigned short)f2bf(a0.y) | ((unsigned)(unsigned short)f2bf(b0.y) << 16);
    }

    __syncthreads();  // prior iteration's K/VT LDS reads complete

    {
      const int base = krow * 64 + kd;
      const int sw = (krow & 7) << 3;
      *(bf16x4*)&Ksh[base ^ sw] = kw;   // 4-short aligned; XOR bits >= 3 preserve alignment
    }
    {
      unsigned* vt32 = (unsigned*)VTsh;
      #pragma unroll
      for (int j = 0; j < 2; ++j) {
        const int R = vd + j;
        vt32[R * 32 + ((vrow >> 1) ^ ((R & 7) << 2))] = vpk[j];
      }
    }

    // ---- bias for this tile (use-site; TLP hides it — R10-proven) ----
    float br[4][4];
    #pragma unroll
    for (int r = 0; r < 4; ++r)
      #pragma unroll
      for (int tt = 0; tt < 4; ++tt)
        br[r][tt] = bb[(size_t)r * NS + t0 + tt * 16];

    __syncthreads();  // K/VT tile visible in LDS

    __builtin_amdgcn_s_setprio(1);
    // ---- QK^T: acc init = bias*log2e - 8*log2e ----
    f32x4 sacc[4];
    #pragma unroll
    for (int tt = 0; tt < 4; ++tt) {
      f32x4 sb;
      #pragma unroll
      for (int r = 0; r < 4; ++r) sb[r] = fmaf(br[r][tt], LOG2E, -8.f * LOG2E);
      const int kr = tt * 16 + lo;
      const int ksw = (kr & 7) << 3;
      bf16x8 k0 = *(const bf16x8*)&Ksh[(kr * 64      + hi * 8) ^ ksw];
      bf16x8 k1 = *(const bf16x8*)&Ksh[(kr * 64 + 32 + hi * 8) ^ ksw];
      sb = __builtin_amdgcn_mfma_f32_16x16x32_bf16(qf[0], k0, sb, 0, 0, 0);
      sb = __builtin_amdgcn_mfma_f32_16x16x32_bf16(qf[1], k1, sb, 0, 0, 0);
      sacc[tt] = sb;
    }

    // ---- P = exp2(s), per-lane f32 psum, per-wave P strip ----
    short* pw = Psh[w];
    #pragma unroll
    for (int r = 0; r < 4; ++r) {
      const int row = hi * 4 + r;
      const int sw = (row & 7) << 3;
      #pragma unroll
      for (int tt = 0; tt < 4; ++tt) {
        float p = fast_exp2(sacc[tt][r]);
        psum[r] += p;
        pw[row * 64 + ((tt * 16 + lo) ^ sw)] = f2bf(p);
      }
    }
    asm volatile("s_waitcnt lgkmcnt(0)" ::: "memory");

    // ---- PV ----
    bf16x8 pf0, pf1;
    {
      const int psw = (lo & 7) << 3;
      pf0 = *(const bf16x8*)&pw[lo * 64 + ((     hi * 8) ^ psw)];
      pf1 = *(const bf16x8*)&pw[lo * 64 + ((32 + hi * 8) ^ psw)];
    }
    #pragma unroll
    for (int dt = 0; dt < 4; ++dt) {
      const int vr = dt * 16 + lo;
      const int vsw = (vr & 7) << 3;
      bf16x8 v0 = *(const bf16x8*)&VTsh[vr * 64 + ((     hi * 8) ^ vsw)];
      bf16x8 v1 = *(const bf16x8*)&VTsh[vr * 64 + ((32 + hi * 8) ^ vsw)];
      oacc[dt] = __builtin_amdgcn_mfma_f32_16x16x32_bf16(pf0, v0, oacc[dt], 0, 0, 0);
      oacc[dt] = __builtin_amdgcn_mfma_f32_16x16x32_bf16(pf1, v1, oacc[dt], 0, 0, 0);
    }
    __builtin_amdgcn_s_setprio(0);
  }

  // ---- final row-sum reduction (once) ----
  #pragma unroll
  for (int r = 0; r < 4; ++r) {
    psum[r] += __shfl_xor(psum[r], 1, 64);
    psum[r] += __shfl_xor(psum[r], 2, 64);
    psum[r] += __shfl_xor(psum[r], 4, 64);
    psum[r] += __shfl_xor(psum[r], 8, 64);
  }

  // ---- epilogue: out[b][s][h][d] ----
  float* ob = out + ((size_t)(b * NS + q0 + w * 16 + hi * 4) * NH + h) * ND + lo;
  #pragma unroll
  for (int r = 0; r < 4; ++r) {
    float inv = 1.f / psum[r];
    #pragma unroll
    for (int dt = 0; dt < 4; ++dt)
      ob[(size_t)r * NH * ND + dt * 16] = oacc[dt][r] * inv;
  }
}

extern "C" void kernel_launch(void* const* d_in, const int* in_sizes, int n_in,
                              void* d_out, int out_size, void* d_ws, size_t ws_size,
                              hipStream_t stream) {
  const float* qkv  = (const float*)d_in[0];
  const float* bias = (const float*)d_in[1];
  float* out = (float*)d_out;
  dim3 grid(NB * NH * (NS / 256));   // 256 blocks
  fsa_fwd<<<grid, 1024, 0, stream>>>(qkv, bias, out);
}